// Round 10
// baseline (1456.539 us; speedup 1.0000x reference)
//
#include <hip/hip_runtime.h>
#include <hip/hip_bf16.h>
#include <math.h>

#define NTOK   196
#define BATCH  64
#define TOKENS (BATCH*NTOK)   // 12544
#define DIMD   1024
#define PD     768
#define HEADS  8
#define HD     128
#define DEPTH  6
#define LN_EPS 1e-5f
#define APAD_R 256            // padded A rows per batch (for 128-tiles)
#define APAD_C 224            // padded K dim for A@G (7*32)

typedef __hip_bfloat16 bf16;
typedef __attribute__((ext_vector_type(8))) short bf16x8;
typedef __attribute__((ext_vector_type(4))) float f32x4;

typedef const __attribute__((address_space(1))) void* gptr_t;
typedef __attribute__((address_space(3))) void* lptr_t;

__device__ __forceinline__ void gl_lds16(const bf16* g, bf16* l) {
  __builtin_amdgcn_global_load_lds((gptr_t)(const void*)g, (lptr_t)(void*)l, 16, 0, 0);
}
__device__ __forceinline__ unsigned short bfbits(float f) {
  bf16 h = __float2bfloat16(f);
  return *(unsigned short*)&h;
}

// ================= generic MFMA GEMM: C[m][n] = sum_k A[m][k] * Bt[n][k] =================
// 128x128 tile, BK=32. mode 0: Cf = acc*alpha (+bias)(+bf16 res); mode 1: Cb = bf16(acc)
__global__ __launch_bounds__(256) void gemm_mfma(
    const bf16* __restrict__ A, int lda, long aStride,
    const bf16* __restrict__ Bt, int ldb, long bStride,
    int K, int mode,
    float* __restrict__ Cf, bf16* __restrict__ Cb, int ldc, long cStride,
    const float* __restrict__ bias, const bf16* __restrict__ resb, long resStride,
    float alpha, int Mb, int Nb) {
  __shared__ __align__(16) bf16 As[128*32];
  __shared__ __align__(16) bf16 Bs[128*32];
  const int z = blockIdx.z;
  A  += (long)z*aStride;
  Bt += (long)z*bStride;
  const int m0 = blockIdx.y*128, n0 = blockIdx.x*128;
  const int tid = threadIdx.x, lane = tid & 63, wv = tid >> 6;
  const int lrow = lane >> 2, lchunk = lane & 3;
  const bf16* ga = A + (long)(m0 + wv*32 + lrow)*lda + lchunk*8;
  const bf16* gb = Bt + (long)(n0 + wv*32 + lrow)*ldb + lchunk*8;
  bf16* lA = As + (wv*32)*32;
  bf16* lB = Bs + (wv*32)*32;
  const int mBase = (wv & 1)*64, nBase = (wv >> 1)*64;
  const int fr = lane & 15, fq = lane >> 4;

  f32x4 acc[4][4];
  #pragma unroll
  for (int i = 0; i < 4; i++)
    #pragma unroll
    for (int j = 0; j < 4; j++) acc[i][j] = (f32x4){0.f,0.f,0.f,0.f};

  for (int k0 = 0; k0 < K; k0 += 32) {
    gl_lds16(ga + k0,            lA);
    gl_lds16(ga + k0 + 16*lda,   lA + 16*32);
    gl_lds16(gb + k0,            lB);
    gl_lds16(gb + k0 + 16*ldb,   lB + 16*32);
    asm volatile("s_waitcnt vmcnt(0)" ::: "memory");
    __syncthreads();
    bf16x8 af[4], bfr[4];
    #pragma unroll
    for (int mi = 0; mi < 4; mi++)
      af[mi] = *(const bf16x8*)(As + (mBase + mi*16 + fr)*32 + fq*8);
    #pragma unroll
    for (int ni = 0; ni < 4; ni++)
      bfr[ni] = *(const bf16x8*)(Bs + (nBase + ni*16 + fr)*32 + fq*8);
    #pragma unroll
    for (int mi = 0; mi < 4; mi++)
      #pragma unroll
      for (int ni = 0; ni < 4; ni++)
        acc[mi][ni] = __builtin_amdgcn_mfma_f32_16x16x32_bf16(af[mi], bfr[ni], acc[mi][ni], 0, 0, 0);
    __syncthreads();
  }

  #pragma unroll
  for (int mi = 0; mi < 4; mi++)
    #pragma unroll
    for (int ni = 0; ni < 4; ni++)
      #pragma unroll
      for (int r = 0; r < 4; r++) {
        int gm = m0 + mBase + mi*16 + fq*4 + r;
        int gn = n0 + nBase + ni*16 + fr;
        if (gm >= Mb || gn >= Nb) continue;
        float v = acc[mi][ni][r] * alpha;
        if (mode == 0) {
          if (bias) v += bias[gn];
          if (resb) v += __bfloat162float(resb[(long)z*resStride + (long)gm*ldc + gn]);
          Cf[(long)z*cStride + (long)gm*ldc + gn] = v;
        } else {
          Cb[(long)z*cStride + (long)gm*ldc + gn] = __float2bfloat16(v);
        }
      }
}

// ====== A@G single-barrier: x[z][m][n] = sum_k Apad[z][m][k]*Gt[z][n][k] + xnb, K=224 resident ======
__global__ __launch_bounds__(256) void gemm_ag(
    const bf16* __restrict__ Apad, const bf16* __restrict__ Gt,
    const bf16* __restrict__ xnb, float* __restrict__ x) {
  __shared__ __align__(16) bf16 As[7*128*32];   // 56 KB, chunk-major [c][row][32]
  __shared__ __align__(16) bf16 Bs[7*128*32];   // 56 KB
  const int z = blockIdx.z;
  const int m0 = blockIdx.y*128, n0 = blockIdx.x*128;
  const bf16* A  = Apad + (long)z*APAD_R*APAD_C;   // [256][224] (rows/cols >=196 are 0)
  const bf16* Bt = Gt   + (long)z*DIMD*APAD_C;     // [1024][224] (cols >=196 are 0)
  const int tid = threadIdx.x, lane = tid & 63, wv = tid >> 6;
  const int lrow = lane >> 2, lchunk = lane & 3;
  const bf16* ga = A  + (long)(m0 + wv*32 + lrow)*APAD_C + lchunk*8;
  const bf16* gb = Bt + (long)(n0 + wv*32 + lrow)*APAD_C + lchunk*8;
  bf16* lA = As + (wv*32)*32;
  bf16* lB = Bs + (wv*32)*32;
  const int mBase = (wv & 1)*64, nBase = (wv >> 1)*64;
  const int fr = lane & 15, fq = lane >> 4;

  #pragma unroll
  for (int c = 0; c < 7; c++) {
    gl_lds16(ga + c*32,             lA + c*4096);
    gl_lds16(ga + c*32 + 16*APAD_C, lA + c*4096 + 16*32);
    gl_lds16(gb + c*32,             lB + c*4096);
    gl_lds16(gb + c*32 + 16*APAD_C, lB + c*4096 + 16*32);
  }
  asm volatile("s_waitcnt vmcnt(0)" ::: "memory");
  __syncthreads();

  f32x4 acc[4][4];
  #pragma unroll
  for (int i = 0; i < 4; i++)
    #pragma unroll
    for (int j = 0; j < 4; j++) acc[i][j] = (f32x4){0.f,0.f,0.f,0.f};

  #pragma unroll
  for (int c = 0; c < 7; c++) {
    bf16x8 af[4], bfr[4];
    #pragma unroll
    for (int mi = 0; mi < 4; mi++)
      af[mi] = *(const bf16x8*)(As + c*4096 + (mBase + mi*16 + fr)*32 + fq*8);
    #pragma unroll
    for (int ni = 0; ni < 4; ni++)
      bfr[ni] = *(const bf16x8*)(Bs + c*4096 + (nBase + ni*16 + fr)*32 + fq*8);
    #pragma unroll
    for (int mi = 0; mi < 4; mi++)
      #pragma unroll
      for (int ni = 0; ni < 4; ni++)
        acc[mi][ni] = __builtin_amdgcn_mfma_f32_16x16x32_bf16(af[mi], bfr[ni], acc[mi][ni], 0, 0, 0);
  }

  #pragma unroll
  for (int mi = 0; mi < 4; mi++)
    #pragma unroll
    for (int ni = 0; ni < 4; ni++)
      #pragma unroll
      for (int r = 0; r < 4; r++) {
        int gm = m0 + mBase + mi*16 + fq*4 + r;
        int gn = n0 + nBase + ni*16 + fr;
        if (gm >= NTOK) continue;
        float v = acc[mi][ni][r]
                + __bfloat162float(xnb[((long)z*NTOK + gm)*DIMD + gn]);
        x[((long)z*NTOK + gm)*DIMD + gn] = v;
      }
}

// ====== fused QKT+softmax: per batch z, 64-row tile x full 224-col width ======
__global__ __launch_bounds__(256) void gemm_qs(
    const bf16* __restrict__ xmp, const bf16* __restrict__ xnbp,
    bf16* __restrict__ Apad, float scale) {
  __shared__ __align__(16) bf16 As[64*32];
  __shared__ __align__(16) bf16 Bs[224*32];
  const int z = blockIdx.z;
  const int y0 = blockIdx.y*64;                 // 0,64,128,192
  const bf16* A  = xmp  + (long)z*NTOK*DIMD;
  const bf16* Bt = xnbp + (long)z*NTOK*DIMD;
  const int tid = threadIdx.x, lane = tid & 63, wv = tid >> 6;
  const int lrow = lane >> 2, lchunk = lane & 3;
  const bf16* ga = A + (long)(y0 + wv*16 + lrow)*DIMD + lchunk*8;
  bf16* lA = As + (wv*16)*32;
  const bf16* gb = Bt + (long)(wv*64 + lrow)*DIMD + lchunk*8;
  bf16* lB = Bs + (wv*64)*32;
  const int nIss = (wv < 3) ? 4 : 2;
  const int fr = lane & 15, fq = lane >> 4;

  f32x4 acc[14];
  #pragma unroll
  for (int j = 0; j < 14; j++) acc[j] = (f32x4){0.f,0.f,0.f,0.f};

  for (int k0 = 0; k0 < 1024; k0 += 32) {
    gl_lds16(ga + k0, lA);
    for (int i = 0; i < nIss; i++)
      gl_lds16(gb + k0 + (long)i*16*DIMD, lB + i*16*32);
    asm volatile("s_waitcnt vmcnt(0)" ::: "memory");
    __syncthreads();
    bf16x8 af = *(const bf16x8*)(As + (wv*16 + fr)*32 + fq*8);
    #pragma unroll
    for (int j = 0; j < 14; j++) {
      bf16x8 bfr = *(const bf16x8*)(Bs + (j*16 + fr)*32 + fq*8);
      acc[j] = __builtin_amdgcn_mfma_f32_16x16x32_bf16(af, bfr, acc[j], 0, 0, 0);
    }
    __syncthreads();
  }

  #pragma unroll
  for (int r = 0; r < 4; r++) {
    float mx = -INFINITY;
    #pragma unroll
    for (int j = 0; j < 14; j++) {
      int col = j*16 + fr;
      if (col < NTOK) mx = fmaxf(mx, acc[j][r]);
    }
    #pragma unroll
    for (int off = 1; off < 16; off <<= 1) mx = fmaxf(mx, __shfl_xor(mx, off));
    float e[14];
    float s = 0.f;
    #pragma unroll
    for (int j = 0; j < 14; j++) {
      int col = j*16 + fr;
      e[j] = (col < NTOK) ? __expf((acc[j][r] - mx) * scale) : 0.f;
      s += e[j];
    }
    #pragma unroll
    for (int off = 1; off < 16; off <<= 1) s += __shfl_xor(s, off);
    float inv = 1.f / s;
    int grow = y0 + wv*16 + fq*4 + r;
    bf16* dst = Apad + ((long)z*APAD_R + grow)*APAD_C;
    #pragma unroll
    for (int j = 0; j < 14; j++) {
      int col = j*16 + fr;
      float outv = (grow < NTOK) ? e[j]*inv : 0.f;
      dst[col] = __float2bfloat16(outv);
    }
  }
}

// ====== V-GEMM direct-Gt: Gt[z][h*128+d][t] = sum_e WVt[d][e]*xnb[z*196+t][h*128+e] ======
__global__ __launch_bounds__(256) void gemm_v(
    const bf16* __restrict__ WVt, const bf16* __restrict__ xnb, bf16* __restrict__ Gt) {
  __shared__ __align__(16) bf16 As[128*32];
  __shared__ __align__(16) bf16 Bs[128*32];
  const int z = blockIdx.z, h = blockIdx.y, n0 = blockIdx.x*128;
  const int tid = threadIdx.x, lane = tid & 63, wv = tid >> 6;
  const int lrow = lane >> 2, lchunk = lane & 3;
  const bf16* ga = WVt + (long)(wv*32 + lrow)*HD + lchunk*8;
  const bf16* gb = xnb + (long)(z*NTOK + n0 + wv*32 + lrow)*DIMD + h*HD + lchunk*8;
  bf16* lA = As + (wv*32)*32;
  bf16* lB = Bs + (wv*32)*32;
  const int mBase = (wv & 1)*64, nBase = (wv >> 1)*64;
  const int fr = lane & 15, fq = lane >> 4;

  f32x4 acc[4][4];
  #pragma unroll
  for (int i = 0; i < 4; i++)
    #pragma unroll
    for (int j = 0; j < 4; j++) acc[i][j] = (f32x4){0.f,0.f,0.f,0.f};

  for (int k0 = 0; k0 < HD; k0 += 32) {
    gl_lds16(ga + k0,           lA);
    gl_lds16(ga + k0 + 16*HD,   lA + 16*32);
    gl_lds16(gb + k0,           lB);
    gl_lds16(gb + k0 + 16*DIMD, lB + 16*32);
    asm volatile("s_waitcnt vmcnt(0)" ::: "memory");
    __syncthreads();
    bf16x8 af[4], bfr[4];
    #pragma unroll
    for (int mi = 0; mi < 4; mi++)
      af[mi] = *(const bf16x8*)(As + (mBase + mi*16 + fr)*32 + fq*8);
    #pragma unroll
    for (int ni = 0; ni < 4; ni++)
      bfr[ni] = *(const bf16x8*)(Bs + (nBase + ni*16 + fr)*32 + fq*8);
    #pragma unroll
    for (int mi = 0; mi < 4; mi++)
      #pragma unroll
      for (int ni = 0; ni < 4; ni++)
        acc[mi][ni] = __builtin_amdgcn_mfma_f32_16x16x32_bf16(af[mi], bfr[ni], acc[mi][ni], 0, 0, 0);
    __syncthreads();
  }

  #pragma unroll
  for (int mi = 0; mi < 4; mi++)
    #pragma unroll
    for (int ni = 0; ni < 4; ni++)
      #pragma unroll
      for (int r = 0; r < 4; r++) {
        int gm = mBase + mi*16 + fq*4 + r;          // output dim within head (0..127)
        int gn = n0 + nBase + ni*16 + fr;           // token
        if (gn < NTOK)
          Gt[((long)z*DIMD + h*HD + gm)*APAD_C + gn] = __float2bfloat16(acc[mi][ni][r]);
        else if (gn < APAD_C)
          Gt[((long)z*DIMD + h*HD + gm)*APAD_C + gn] = __float2bfloat16(0.f);
      }
}

// ================= classifier split-K =================
__global__ __launch_bounds__(256) void gemm_cls(
    const bf16* __restrict__ A, const bf16* __restrict__ Bt,
    float* __restrict__ Cp) {
  __shared__ __align__(16) bf16 As[64*32];
  __shared__ __align__(16) bf16 Bs[128*32];
  const int n0 = blockIdx.x*128, kz = blockIdx.y;
  const int tid = threadIdx.x, lane = tid & 63, wv = tid >> 6;
  const bf16* ga = A + (tid>>2)*DIMD + kz*128 + (tid&3)*8;
  const bf16* gb = Bt + (long)(n0 + wv*32 + (lane>>2))*DIMD + kz*128 + (lane&3)*8;
  bf16* lA = As + wv*512;
  bf16* lB = Bs + (wv*32)*32;
  const int fr = lane & 15, fq = lane >> 4;
  f32x4 acc[4][2];
  #pragma unroll
  for (int i = 0; i < 4; i++)
    #pragma unroll
    for (int j = 0; j < 2; j++) acc[i][j] = (f32x4){0.f,0.f,0.f,0.f};
  for (int it = 0; it < 4; it++) {
    gl_lds16(ga + it*32, lA);
    gl_lds16(gb + it*32,            lB);
    gl_lds16(gb + it*32 + 16*DIMD,  lB + 16*32);
    asm volatile("s_waitcnt vmcnt(0)" ::: "memory");
    __syncthreads();
    bf16x8 af[4], bfr[2];
    #pragma unroll
    for (int mi = 0; mi < 4; mi++)
      af[mi] = *(const bf16x8*)(As + (mi*16 + fr)*32 + fq*8);
    #pragma unroll
    for (int ni = 0; ni < 2; ni++)
      bfr[ni] = *(const bf16x8*)(Bs + (wv*32 + ni*16 + fr)*32 + fq*8);
    #pragma unroll
    for (int mi = 0; mi < 4; mi++)
      #pragma unroll
      for (int ni = 0; ni < 2; ni++)
        acc[mi][ni] = __builtin_amdgcn_mfma_f32_16x16x32_bf16(af[mi], bfr[ni], acc[mi][ni], 0, 0, 0);
    __syncthreads();
  }
  #pragma unroll
  for (int mi = 0; mi < 4; mi++)
    #pragma unroll
    for (int ni = 0; ni < 2; ni++)
      #pragma unroll
      for (int r = 0; r < 4; r++) {
        int gm = mi*16 + fq*4 + r;
        int gn = n0 + wv*32 + ni*16 + fr;
        Cp[((long)kz*64 + gm)*DIMD + gn] = acc[mi][ni][r];
      }
}

__global__ __launch_bounds__(256) void cls_reduce(
    const float* __restrict__ Cp, const float* __restrict__ bias,
    float* __restrict__ out) {
  int i = blockIdx.x*256 + threadIdx.x;
  int m = i / 1000, n = i - m*1000;
  float s = bias[n];
  #pragma unroll
  for (int kz = 0; kz < 8; kz++) s += Cp[((long)kz*64 + m)*DIMD + n];
  out[i] = s;
}

// ================= patchify + LN1 (dim 768) -> bf16 =================
__global__ __launch_bounds__(256) void patchify_ln(
    const float* __restrict__ img, const float* __restrict__ g,
    const float* __restrict__ b, bf16* __restrict__ out) {
  int t = blockIdx.x;
  int bi = t / NTOK, n = t % NTOK;
  int ph = n / 14, pw = n % 14;
  __shared__ float vals[PD];
  __shared__ float red[256];
  int tid = threadIdx.x;
  for (int j = tid; j < PD; j += 256) {
    int p1 = j / 48, rem = j % 48, p2 = rem / 3, c = rem % 3;
    vals[j] = img[(((long)bi*3 + c)*224 + (ph*16 + p1))*224 + (pw*16 + p2)];
  }
  __syncthreads();
  float s = 0.f;
  for (int j = tid; j < PD; j += 256) s += vals[j];
  red[tid] = s; __syncthreads();
  for (int st = 128; st > 0; st >>= 1) { if (tid < st) red[tid] += red[tid+st]; __syncthreads(); }
  float mean = red[0] / (float)PD;
  __syncthreads();
  float s2 = 0.f;
  for (int j = tid; j < PD; j += 256) { float d = vals[j]-mean; s2 += d*d; }
  red[tid] = s2; __syncthreads();
  for (int st = 128; st > 0; st >>= 1) { if (tid < st) red[tid] += red[tid+st]; __syncthreads(); }
  float rstd = rsqrtf(red[0]/(float)PD + LN_EPS);
  for (int j = tid; j < PD; j += 256)
    out[(long)t*PD + j] = __float2bfloat16((vals[j]-mean)*rstd*g[j] + b[j]);
}

// ================= LayerNorm rows (dim=1024): optional fp32 out, optional bf16 out =================
__global__ __launch_bounds__(256) void ln_rows2(
    const float* __restrict__ in, const float* __restrict__ g,
    const float* __restrict__ b, const float* __restrict__ pos,
    float* __restrict__ outf, ushort4* __restrict__ outb) {
  long t = blockIdx.x;
  int tid = threadIdx.x;
  float4 v = ((const float4*)(in + t*DIMD))[tid];
  float s  = v.x+v.y+v.z+v.w;
  float s2 = v.x*v.x+v.y*v.y+v.z*v.z+v.w*v.w;
  __shared__ float rs[256], rq[256];
  rs[tid]=s; rq[tid]=s2; __syncthreads();
  for (int st = 128; st > 0; st >>= 1) {
    if (tid < st) { rs[tid]+=rs[tid+st]; rq[tid]+=rq[tid+st]; }
    __syncthreads();
  }
  float mean = rs[0]*(1.f/1024.f);
  float var  = rq[0]*(1.f/1024.f) - mean*mean;
  float rstd = rsqrtf(var + LN_EPS);
  float4 gg = ((const float4*)g)[tid];
  float4 bb = ((const float4*)b)[tid];
  float4 o;
  o.x = (v.x-mean)*rstd*gg.x + bb.x;
  o.y = (v.y-mean)*rstd*gg.y + bb.y;
  o.z = (v.z-mean)*rstd*gg.z + bb.z;
  o.w = (v.w-mean)*rstd*gg.w + bb.w;
  if (pos) {
    float4 pp = ((const float4*)(pos + (long)(t % NTOK)*DIMD))[tid];
    o.x += pp.x; o.y += pp.y; o.z += pp.z; o.w += pp.w;
  }
  if (outf) ((float4*)(outf + t*DIMD))[tid] = o;
  if (outb) {
    ushort4 u;
    u.x = bfbits(o.x); u.y = bfbits(o.y); u.z = bfbits(o.z); u.w = bfbits(o.w);
    outb[t*256 + tid] = u;
  }
}

// ================= cast + transpose weights: fp32 [R][C] -> bf16 [C][R] =================
__global__ void castT(const float* __restrict__ src, bf16* __restrict__ dst, int R, int C) {
  __shared__ float t[32][33];
  int rb = blockIdx.y*32, cb = blockIdx.x*32;
  int tx = threadIdx.x, ty = threadIdx.y;  // (32,8)
  for (int i = ty; i < 32; i += 8)
    if (rb+i < R && cb+tx < C) t[i][tx] = src[(long)(rb+i)*C + cb+tx];
  __syncthreads();
  for (int i = ty; i < 32; i += 8)
    if (cb+i < C && rb+tx < R) dst[(long)(cb+i)*R + rb+tx] = __float2bfloat16(t[tx][i]);
}

// ================= natural cast fp32 -> bf16 (elementwise, float4) =================
__global__ __launch_bounds__(256) void castN(
    const float* __restrict__ src, ushort4* __restrict__ dst) {
  int i = blockIdx.x*256 + threadIdx.x;
  float4 v = ((const float4*)src)[i];
  ushort4 u;
  u.x = bfbits(v.x); u.y = bfbits(v.y); u.z = bfbits(v.z); u.w = bfbits(v.w);
  dst[i] = u;
}

// ================= mean over tokens -> bf16 =================
__global__ __launch_bounds__(256) void mean_tokens(
    const float* __restrict__ x, bf16* __restrict__ outb) {
  int b = blockIdx.x;
  int d = blockIdx.y*256 + threadIdx.x;
  const float* p = x + (long)b*NTOK*DIMD + d;
  float s = 0.f;
  #pragma unroll 4
  for (int n = 0; n < NTOK; n++) s += p[(long)n*DIMD];
  outb[(long)b*DIMD + d] = __float2bfloat16(s * (1.f/196.f));
}

extern "C" void kernel_launch(void* const* d_in, const int* in_sizes, int n_in,
                              void* d_out, int out_size, void* d_ws, size_t ws_size,
                              hipStream_t stream) {
  (void)in_sizes; (void)n_in; (void)out_size; (void)ws_size;
  const float* image = (const float*)d_in[0];
  const float* ln1_g = (const float*)d_in[1];
  const float* ln1_b = (const float*)d_in[2];
  const float* W_emb = (const float*)d_in[3];
  const float* b_emb = (const float*)d_in[4];
  const float* ln2_g = (const float*)d_in[5];
  const float* ln2_b = (const float*)d_in[6];
  const float* pos   = (const float*)d_in[7];
  const float* norm_g= (const float*)d_in[8];
  const float* norm_b= (const float*)d_in[9];
  const float* WV    = (const float*)d_in[10];
  const float* WK    = (const float*)d_in[11];
  const float* WQ    = (const float*)d_in[12];
  const float* lastW = (const float*)d_in[13];
  const float* lastb = (const float*)d_in[14];
  float* out = (float*)d_out;

  char* W = (char*)d_ws;
  float* x     = (float*)(W);                      // 51,380,224
  bf16*  xnb   = (bf16*) (W + 51380224);           // 25,690,112
  bf16*  xm    = (bf16*) (W + 77070336);           // 25.7MB in 51.6MB slab (alias Xp; overread zone)
  bf16*  Xp    = xm;
  // slabB: embed-phase xn (fp32 51.4 MB) OR layer-phase Gt+Apad
  float* xn    = (float*)(W + 128712704);
  bf16*  Gt    = (bf16*) (W + 128712704);          // 29,360,128
  bf16*  Apad  = (bf16*) (W + 167907328);          //  7,340,032
  bf16*  WembT = (bf16*) (W + 180092928);          //  1,572,864
  bf16*  WQb   = (bf16*) (W + 181665792);          //  2,097,152 (natural layout)
  bf16*  WKb   = (bf16*) (W + 183762944);          //  2,097,152 (natural layout)
  bf16*  WVt   = (bf16*) (W + 185860096);          //     32,768
  bf16*  lastWT= (bf16*) (W + 185892864);          //  2,097,152
  bf16*  meanxb= (bf16*) (W + 187990016);          //    131,072
  float* clsPart=(float*)(W + 188121088);          //  2,097,152
  bf16*  Mt    = (bf16*) (W + 190218240);          //  2,097,152 (M^T = WK @ WQ^T)

  dim3 blk(256);
  const float scale = 0.08838834764831845f;  // 128^-0.5
  const long ZR = 0;

  // weight casts
  castT<<<dim3(32, 24), dim3(32, 8), 0, stream>>>(W_emb, WembT, PD, DIMD);
  castN<<<1024, blk, 0, stream>>>(WQ, (ushort4*)WQb);
  castN<<<1024, blk, 0, stream>>>(WK, (ushort4*)WKb);
  castT<<<dim3(4, 4),  dim3(32, 8), 0, stream>>>(WV, WVt, HD, HD);
  castT<<<dim3(32, 32), dim3(32, 8), 0, stream>>>(lastW, lastWT, DIMD, 1000);
  // Mt[j][i] = sum_k WK[j][k]*WQ[i][k]  (= (WQ @ WK^T)^T)
  gemm_mfma<<<dim3(8, 8, 1), blk, 0, stream>>>(
      WKb, DIMD, ZR, WQb, DIMD, ZR, DIMD, 1,
      nullptr, Mt, DIMD, ZR, nullptr, nullptr, ZR, 1.f, DIMD, DIMD);

  // patch embed
  patchify_ln<<<TOKENS, blk, 0, stream>>>(image, ln1_g, ln1_b, Xp);
  gemm_mfma<<<dim3(8, 98, 1), blk, 0, stream>>>(
      Xp, PD, ZR, WembT, PD, ZR, PD, 0,
      xn, nullptr, DIMD, ZR, b_emb, nullptr, ZR, 1.f, TOKENS, DIMD);
  ln_rows2<<<TOKENS, blk, 0, stream>>>(xn, ln2_g, ln2_b, pos, x, nullptr);

  for (int l = 0; l < DEPTH; l++) {
    // xnb = bf16(LN(x))
    ln_rows2<<<TOKENS, blk, 0, stream>>>(x, norm_g, norm_b, nullptr, nullptr, (ushort4*)xnb);
    // xm = xnb @ M
    gemm_mfma<<<dim3(8, 98, 1), blk, 0, stream>>>(
        xnb, DIMD, ZR, Mt, DIMD, ZR, DIMD, 1,
        nullptr, xm, DIMD, ZR, nullptr, nullptr, ZR, 1.f, TOKENS, DIMD);
    // Apad = softmax(xm @ xnb^T * scale), fused, pads zeroed
    gemm_qs<<<dim3(1, 4, BATCH), blk, 0, stream>>>(xm, xnb, Apad, scale);
    // Gt[b][dim][tok] = WV^T @ xn^T  (direct transposed layout, pad cols zeroed)
    gemm_v<<<dim3(2, HEADS, BATCH), blk, 0, stream>>>(WVt, xnb, Gt);
    // x = Apad @ G + xnb  (single-barrier K-resident kernel)
    gemm_ag<<<dim3(8, 2, BATCH), blk, 0, stream>>>(Apad, Gt, xnb, x);
  }

  // classifier
  mean_tokens<<<dim3(BATCH, 4), blk, 0, stream>>>(x, meanxb);
  gemm_cls<<<dim3(8, 8), blk, 0, stream>>>(meanxb, lastWT, clsPart);
  cls_reduce<<<250, blk, 0, stream>>>(clsPart, lastb, out);
}

// Round 11
// 1370.820 us; speedup vs baseline: 1.0625x; 1.0625x over previous
//
#include <hip/hip_runtime.h>
#include <hip/hip_bf16.h>
#include <math.h>

#define NTOK   196
#define BATCH  64
#define TOKENS (BATCH*NTOK)   // 12544
#define DIMD   1024
#define PD     768
#define HEADS  8
#define HD     128
#define DEPTH  6
#define LN_EPS 1e-5f
#define APAD_R 256            // padded A rows per batch (for 128-tiles)
#define APAD_C 224            // padded K dim for A@G (7*32)

typedef __hip_bfloat16 bf16;
typedef __attribute__((ext_vector_type(8))) short bf16x8;
typedef __attribute__((ext_vector_type(4))) float f32x4;

typedef const __attribute__((address_space(1))) void* gptr_t;
typedef __attribute__((address_space(3))) void* lptr_t;

__device__ __forceinline__ void gl_lds16(const bf16* g, bf16* l) {
  __builtin_amdgcn_global_load_lds((gptr_t)(const void*)g, (lptr_t)(void*)l, 16, 0, 0);
}
__device__ __forceinline__ unsigned short bfbits(float f) {
  bf16 h = __float2bfloat16(f);
  return *(unsigned short*)&h;
}
__device__ __forceinline__ float b2f(unsigned short u) {
  bf16 h; *(unsigned short*)&h = u;
  return __bfloat162float(h);
}

// ================= generic MFMA GEMM: C[m][n] = sum_k A[m][k] * Bt[n][k] =================
// 128x128 tile, BK=32. v = acc*alpha (+bias)(+bf16 res); mode 0: fp32 out, mode 1: bf16 out
__global__ __launch_bounds__(256) void gemm_mfma(
    const bf16* __restrict__ A, int lda, long aStride,
    const bf16* __restrict__ Bt, int ldb, long bStride,
    int K, int mode,
    float* __restrict__ Cf, bf16* __restrict__ Cb, int ldc, long cStride,
    const float* __restrict__ bias, const bf16* __restrict__ resb, long resStride,
    float alpha, int Mb, int Nb) {
  __shared__ __align__(16) bf16 As[128*32];
  __shared__ __align__(16) bf16 Bs[128*32];
  const int z = blockIdx.z;
  A  += (long)z*aStride;
  Bt += (long)z*bStride;
  const int m0 = blockIdx.y*128, n0 = blockIdx.x*128;
  const int tid = threadIdx.x, lane = tid & 63, wv = tid >> 6;
  const int lrow = lane >> 2, lchunk = lane & 3;
  const bf16* ga = A + (long)(m0 + wv*32 + lrow)*lda + lchunk*8;
  const bf16* gb = Bt + (long)(n0 + wv*32 + lrow)*ldb + lchunk*8;
  bf16* lA = As + (wv*32)*32;
  bf16* lB = Bs + (wv*32)*32;
  const int mBase = (wv & 1)*64, nBase = (wv >> 1)*64;
  const int fr = lane & 15, fq = lane >> 4;

  f32x4 acc[4][4];
  #pragma unroll
  for (int i = 0; i < 4; i++)
    #pragma unroll
    for (int j = 0; j < 4; j++) acc[i][j] = (f32x4){0.f,0.f,0.f,0.f};

  for (int k0 = 0; k0 < K; k0 += 32) {
    gl_lds16(ga + k0,            lA);
    gl_lds16(ga + k0 + 16*lda,   lA + 16*32);
    gl_lds16(gb + k0,            lB);
    gl_lds16(gb + k0 + 16*ldb,   lB + 16*32);
    asm volatile("s_waitcnt vmcnt(0)" ::: "memory");
    __syncthreads();
    bf16x8 af[4], bfr[4];
    #pragma unroll
    for (int mi = 0; mi < 4; mi++)
      af[mi] = *(const bf16x8*)(As + (mBase + mi*16 + fr)*32 + fq*8);
    #pragma unroll
    for (int ni = 0; ni < 4; ni++)
      bfr[ni] = *(const bf16x8*)(Bs + (nBase + ni*16 + fr)*32 + fq*8);
    #pragma unroll
    for (int mi = 0; mi < 4; mi++)
      #pragma unroll
      for (int ni = 0; ni < 4; ni++)
        acc[mi][ni] = __builtin_amdgcn_mfma_f32_16x16x32_bf16(af[mi], bfr[ni], acc[mi][ni], 0, 0, 0);
    __syncthreads();
  }

  #pragma unroll
  for (int mi = 0; mi < 4; mi++)
    #pragma unroll
    for (int ni = 0; ni < 4; ni++)
      #pragma unroll
      for (int r = 0; r < 4; r++) {
        int gm = m0 + mBase + mi*16 + fq*4 + r;
        int gn = n0 + nBase + ni*16 + fr;
        if (gm >= Mb || gn >= Nb) continue;
        float v = acc[mi][ni][r] * alpha;
        if (bias) v += bias[gn];
        if (resb) v += __bfloat162float(resb[(long)z*resStride + (long)gm*ldc + gn]);
        if (mode == 0)
          Cf[(long)z*cStride + (long)gm*ldc + gn] = v;
        else
          Cb[(long)z*cStride + (long)gm*ldc + gn] = __float2bfloat16(v);
      }
}

// ====== fused QKT+softmax: per batch z, 64-row tile x full 224-col width ======
__global__ __launch_bounds__(256) void gemm_qs(
    const bf16* __restrict__ xmp, const bf16* __restrict__ xnbp,
    bf16* __restrict__ Apad, float scale) {
  __shared__ __align__(16) bf16 As[64*32];
  __shared__ __align__(16) bf16 Bs[224*32];
  const int z = blockIdx.z;
  const int y0 = blockIdx.y*64;                 // 0,64,128,192
  const bf16* A  = xmp  + (long)z*NTOK*DIMD;
  const bf16* Bt = xnbp + (long)z*NTOK*DIMD;
  const int tid = threadIdx.x, lane = tid & 63, wv = tid >> 6;
  const int lrow = lane >> 2, lchunk = lane & 3;
  const bf16* ga = A + (long)(y0 + wv*16 + lrow)*DIMD + lchunk*8;
  bf16* lA = As + (wv*16)*32;
  const bf16* gb = Bt + (long)(wv*64 + lrow)*DIMD + lchunk*8;
  bf16* lB = Bs + (wv*64)*32;
  const int nIss = (wv < 3) ? 4 : 2;
  const int fr = lane & 15, fq = lane >> 4;

  f32x4 acc[14];
  #pragma unroll
  for (int j = 0; j < 14; j++) acc[j] = (f32x4){0.f,0.f,0.f,0.f};

  for (int k0 = 0; k0 < 1024; k0 += 32) {
    gl_lds16(ga + k0, lA);
    for (int i = 0; i < nIss; i++)
      gl_lds16(gb + k0 + (long)i*16*DIMD, lB + i*16*32);
    asm volatile("s_waitcnt vmcnt(0)" ::: "memory");
    __syncthreads();
    bf16x8 af = *(const bf16x8*)(As + (wv*16 + fr)*32 + fq*8);
    #pragma unroll
    for (int j = 0; j < 14; j++) {
      bf16x8 bfr = *(const bf16x8*)(Bs + (j*16 + fr)*32 + fq*8);
      acc[j] = __builtin_amdgcn_mfma_f32_16x16x32_bf16(af, bfr, acc[j], 0, 0, 0);
    }
    __syncthreads();
  }

  #pragma unroll
  for (int r = 0; r < 4; r++) {
    float mx = -INFINITY;
    #pragma unroll
    for (int j = 0; j < 14; j++) {
      int col = j*16 + fr;
      if (col < NTOK) mx = fmaxf(mx, acc[j][r]);
    }
    #pragma unroll
    for (int off = 1; off < 16; off <<= 1) mx = fmaxf(mx, __shfl_xor(mx, off));
    float e[14];
    float s = 0.f;
    #pragma unroll
    for (int j = 0; j < 14; j++) {
      int col = j*16 + fr;
      e[j] = (col < NTOK) ? __expf((acc[j][r] - mx) * scale) : 0.f;
      s += e[j];
    }
    #pragma unroll
    for (int off = 1; off < 16; off <<= 1) s += __shfl_xor(s, off);
    float inv = 1.f / s;
    int grow = y0 + wv*16 + fq*4 + r;
    bf16* dst = Apad + ((long)z*APAD_R + grow)*APAD_C;
    #pragma unroll
    for (int j = 0; j < 14; j++) {
      int col = j*16 + fr;
      float outv = (grow < NTOK) ? e[j]*inv : 0.f;
      dst[col] = __float2bfloat16(outv);
    }
  }
}

// ====== V-GEMM direct-Gt: Gt[z][h*128+d][t] = sum_e WVt[d][e]*xnb[z*196+t][h*128+e] ======
__global__ __launch_bounds__(256) void gemm_v(
    const bf16* __restrict__ WVt, const bf16* __restrict__ xnb, bf16* __restrict__ Gt) {
  __shared__ __align__(16) bf16 As[128*32];
  __shared__ __align__(16) bf16 Bs[128*32];
  const int z = blockIdx.z, h = blockIdx.y, n0 = blockIdx.x*128;
  const int tid = threadIdx.x, lane = tid & 63, wv = tid >> 6;
  const int lrow = lane >> 2, lchunk = lane & 3;
  const bf16* ga = WVt + (long)(wv*32 + lrow)*HD + lchunk*8;
  const bf16* gb = xnb + (long)(z*NTOK + n0 + wv*32 + lrow)*DIMD + h*HD + lchunk*8;
  bf16* lA = As + (wv*32)*32;
  bf16* lB = Bs + (wv*32)*32;
  const int mBase = (wv & 1)*64, nBase = (wv >> 1)*64;
  const int fr = lane & 15, fq = lane >> 4;

  f32x4 acc[4][4];
  #pragma unroll
  for (int i = 0; i < 4; i++)
    #pragma unroll
    for (int j = 0; j < 4; j++) acc[i][j] = (f32x4){0.f,0.f,0.f,0.f};

  for (int k0 = 0; k0 < HD; k0 += 32) {
    gl_lds16(ga + k0,           lA);
    gl_lds16(ga + k0 + 16*HD,   lA + 16*32);
    gl_lds16(gb + k0,           lB);
    gl_lds16(gb + k0 + 16*DIMD, lB + 16*32);
    asm volatile("s_waitcnt vmcnt(0)" ::: "memory");
    __syncthreads();
    bf16x8 af[4], bfr[4];
    #pragma unroll
    for (int mi = 0; mi < 4; mi++)
      af[mi] = *(const bf16x8*)(As + (mBase + mi*16 + fr)*32 + fq*8);
    #pragma unroll
    for (int ni = 0; ni < 4; ni++)
      bfr[ni] = *(const bf16x8*)(Bs + (nBase + ni*16 + fr)*32 + fq*8);
    #pragma unroll
    for (int mi = 0; mi < 4; mi++)
      #pragma unroll
      for (int ni = 0; ni < 4; ni++)
        acc[mi][ni] = __builtin_amdgcn_mfma_f32_16x16x32_bf16(af[mi], bfr[ni], acc[mi][ni], 0, 0, 0);
    __syncthreads();
  }

  #pragma unroll
  for (int mi = 0; mi < 4; mi++)
    #pragma unroll
    for (int ni = 0; ni < 4; ni++)
      #pragma unroll
      for (int r = 0; r < 4; r++) {
        int gm = mBase + mi*16 + fq*4 + r;          // output dim within head (0..127)
        int gn = n0 + nBase + ni*16 + fr;           // token
        if (gn < NTOK)
          Gt[((long)z*DIMD + h*HD + gm)*APAD_C + gn] = __float2bfloat16(acc[mi][ni][r]);
        else if (gn < APAD_C)
          Gt[((long)z*DIMD + h*HD + gm)*APAD_C + gn] = __float2bfloat16(0.f);
      }
}

// ================= classifier split-K =================
__global__ __launch_bounds__(256) void gemm_cls(
    const bf16* __restrict__ A, const bf16* __restrict__ Bt,
    float* __restrict__ Cp) {
  __shared__ __align__(16) bf16 As[64*32];
  __shared__ __align__(16) bf16 Bs[128*32];
  const int n0 = blockIdx.x*128, kz = blockIdx.y;
  const int tid = threadIdx.x, lane = tid & 63, wv = tid >> 6;
  const bf16* ga = A + (tid>>2)*DIMD + kz*128 + (tid&3)*8;
  const bf16* gb = Bt + (long)(n0 + wv*32 + (lane>>2))*DIMD + kz*128 + (lane&3)*8;
  bf16* lA = As + wv*512;
  bf16* lB = Bs + (wv*32)*32;
  const int fr = lane & 15, fq = lane >> 4;
  f32x4 acc[4][2];
  #pragma unroll
  for (int i = 0; i < 4; i++)
    #pragma unroll
    for (int j = 0; j < 2; j++) acc[i][j] = (f32x4){0.f,0.f,0.f,0.f};
  for (int it = 0; it < 4; it++) {
    gl_lds16(ga + it*32, lA);
    gl_lds16(gb + it*32,            lB);
    gl_lds16(gb + it*32 + 16*DIMD,  lB + 16*32);
    asm volatile("s_waitcnt vmcnt(0)" ::: "memory");
    __syncthreads();
    bf16x8 af[4], bfr[2];
    #pragma unroll
    for (int mi = 0; mi < 4; mi++)
      af[mi] = *(const bf16x8*)(As + (mi*16 + fr)*32 + fq*8);
    #pragma unroll
    for (int ni = 0; ni < 2; ni++)
      bfr[ni] = *(const bf16x8*)(Bs + (wv*32 + ni*16 + fr)*32 + fq*8);
    #pragma unroll
    for (int mi = 0; mi < 4; mi++)
      #pragma unroll
      for (int ni = 0; ni < 2; ni++)
        acc[mi][ni] = __builtin_amdgcn_mfma_f32_16x16x32_bf16(af[mi], bfr[ni], acc[mi][ni], 0, 0, 0);
    __syncthreads();
  }
  #pragma unroll
  for (int mi = 0; mi < 4; mi++)
    #pragma unroll
    for (int ni = 0; ni < 2; ni++)
      #pragma unroll
      for (int r = 0; r < 4; r++) {
        int gm = mi*16 + fq*4 + r;
        int gn = n0 + wv*32 + ni*16 + fr;
        Cp[((long)kz*64 + gm)*DIMD + gn] = acc[mi][ni][r];
      }
}

__global__ __launch_bounds__(256) void cls_reduce(
    const float* __restrict__ Cp, const float* __restrict__ bias,
    float* __restrict__ out) {
  int i = blockIdx.x*256 + threadIdx.x;
  int m = i / 1000, n = i - m*1000;
  float s = bias[n];
  #pragma unroll
  for (int kz = 0; kz < 8; kz++) s += Cp[((long)kz*64 + m)*DIMD + n];
  out[i] = s;
}

// ================= patchify + LN1 (dim 768) -> bf16 =================
__global__ __launch_bounds__(256) void patchify_ln(
    const float* __restrict__ img, const float* __restrict__ g,
    const float* __restrict__ b, bf16* __restrict__ out) {
  int t = blockIdx.x;
  int bi = t / NTOK, n = t % NTOK;
  int ph = n / 14, pw = n % 14;
  __shared__ float vals[PD];
  __shared__ float red[256];
  int tid = threadIdx.x;
  for (int j = tid; j < PD; j += 256) {
    int p1 = j / 48, rem = j % 48, p2 = rem / 3, c = rem % 3;
    vals[j] = img[(((long)bi*3 + c)*224 + (ph*16 + p1))*224 + (pw*16 + p2)];
  }
  __syncthreads();
  float s = 0.f;
  for (int j = tid; j < PD; j += 256) s += vals[j];
  red[tid] = s; __syncthreads();
  for (int st = 128; st > 0; st >>= 1) { if (tid < st) red[tid] += red[tid+st]; __syncthreads(); }
  float mean = red[0] / (float)PD;
  __syncthreads();
  float s2 = 0.f;
  for (int j = tid; j < PD; j += 256) { float d = vals[j]-mean; s2 += d*d; }
  red[tid] = s2; __syncthreads();
  for (int st = 128; st > 0; st >>= 1) { if (tid < st) red[tid] += red[tid+st]; __syncthreads(); }
  float rstd = rsqrtf(red[0]/(float)PD + LN_EPS);
  for (int j = tid; j < PD; j += 256)
    out[(long)t*PD + j] = __float2bfloat16((vals[j]-mean)*rstd*g[j] + b[j]);
}

// ======= LayerNorm rows (dim=1024), fp32 input: optional fp32 out, optional bf16 out =======
__global__ __launch_bounds__(256) void ln_rows2(
    const float* __restrict__ in, const float* __restrict__ g,
    const float* __restrict__ b, const float* __restrict__ pos,
    float* __restrict__ outf, ushort4* __restrict__ outb) {
  long t = blockIdx.x;
  int tid = threadIdx.x;
  float4 v = ((const float4*)(in + t*DIMD))[tid];
  float s  = v.x+v.y+v.z+v.w;
  float s2 = v.x*v.x+v.y*v.y+v.z*v.z+v.w*v.w;
  __shared__ float rs[256], rq[256];
  rs[tid]=s; rq[tid]=s2; __syncthreads();
  for (int st = 128; st > 0; st >>= 1) {
    if (tid < st) { rs[tid]+=rs[tid+st]; rq[tid]+=rq[tid+st]; }
    __syncthreads();
  }
  float mean = rs[0]*(1.f/1024.f);
  float var  = rq[0]*(1.f/1024.f) - mean*mean;
  float rstd = rsqrtf(var + LN_EPS);
  float4 gg = ((const float4*)g)[tid];
  float4 bb = ((const float4*)b)[tid];
  float4 o;
  o.x = (v.x-mean)*rstd*gg.x + bb.x;
  o.y = (v.y-mean)*rstd*gg.y + bb.y;
  o.z = (v.z-mean)*rstd*gg.z + bb.z;
  o.w = (v.w-mean)*rstd*gg.w + bb.w;
  if (pos) {
    float4 pp = ((const float4*)(pos + (long)(t % NTOK)*DIMD))[tid];
    o.x += pp.x; o.y += pp.y; o.z += pp.z; o.w += pp.w;
  }
  if (outf) ((float4*)(outf + t*DIMD))[tid] = o;
  if (outb) {
    ushort4 u;
    u.x = bfbits(o.x); u.y = bfbits(o.y); u.z = bfbits(o.z); u.w = bfbits(o.w);
    outb[t*256 + tid] = u;
  }
}

// ======= LayerNorm rows (dim=1024), bf16 input -> bf16 out (layer-loop variant) =======
__global__ __launch_bounds__(256) void ln_rows_b(
    const ushort4* __restrict__ in, const float* __restrict__ g,
    const float* __restrict__ b, ushort4* __restrict__ outb) {
  long t = blockIdx.x;
  int tid = threadIdx.x;
  ushort4 u = in[t*256 + tid];
  float4 v;
  v.x = b2f(u.x); v.y = b2f(u.y); v.z = b2f(u.z); v.w = b2f(u.w);
  float s  = v.x+v.y+v.z+v.w;
  float s2 = v.x*v.x+v.y*v.y+v.z*v.z+v.w*v.w;
  __shared__ float rs[256], rq[256];
  rs[tid]=s; rq[tid]=s2; __syncthreads();
  for (int st = 128; st > 0; st >>= 1) {
    if (tid < st) { rs[tid]+=rs[tid+st]; rq[tid]+=rq[tid+st]; }
    __syncthreads();
  }
  float mean = rs[0]*(1.f/1024.f);
  float var  = rq[0]*(1.f/1024.f) - mean*mean;
  float rstd = rsqrtf(var + LN_EPS);
  float4 gg = ((const float4*)g)[tid];
  float4 bb = ((const float4*)b)[tid];
  ushort4 o;
  o.x = bfbits((v.x-mean)*rstd*gg.x + bb.x);
  o.y = bfbits((v.y-mean)*rstd*gg.y + bb.y);
  o.z = bfbits((v.z-mean)*rstd*gg.z + bb.z);
  o.w = bfbits((v.w-mean)*rstd*gg.w + bb.w);
  outb[t*256 + tid] = o;
}

// ================= cast + transpose weights: fp32 [R][C] -> bf16 [C][R] =================
__global__ void castT(const float* __restrict__ src, bf16* __restrict__ dst, int R, int C) {
  __shared__ float t[32][33];
  int rb = blockIdx.y*32, cb = blockIdx.x*32;
  int tx = threadIdx.x, ty = threadIdx.y;  // (32,8)
  for (int i = ty; i < 32; i += 8)
    if (rb+i < R && cb+tx < C) t[i][tx] = src[(long)(rb+i)*C + cb+tx];
  __syncthreads();
  for (int i = ty; i < 32; i += 8)
    if (cb+i < C && rb+tx < R) dst[(long)(cb+i)*R + rb+tx] = __float2bfloat16(t[tx][i]);
}

// ================= natural cast fp32 -> bf16 (elementwise, float4) =================
__global__ __launch_bounds__(256) void castN(
    const float* __restrict__ src, ushort4* __restrict__ dst) {
  int i = blockIdx.x*256 + threadIdx.x;
  float4 v = ((const float4*)src)[i];
  ushort4 u;
  u.x = bfbits(v.x); u.y = bfbits(v.y); u.z = bfbits(v.z); u.w = bfbits(v.w);
  dst[i] = u;
}

// ================= mean over tokens (bf16 in) -> bf16 =================
__global__ __launch_bounds__(256) void mean_tokens(
    const bf16* __restrict__ x, bf16* __restrict__ outb) {
  int b = blockIdx.x;
  int d = blockIdx.y*256 + threadIdx.x;
  const bf16* p = x + (long)b*NTOK*DIMD + d;
  float s = 0.f;
  #pragma unroll 4
  for (int n = 0; n < NTOK; n++) s += __bfloat162float(p[(long)n*DIMD]);
  outb[(long)b*DIMD + d] = __float2bfloat16(s * (1.f/196.f));
}

extern "C" void kernel_launch(void* const* d_in, const int* in_sizes, int n_in,
                              void* d_out, int out_size, void* d_ws, size_t ws_size,
                              hipStream_t stream) {
  (void)in_sizes; (void)n_in; (void)out_size; (void)ws_size;
  const float* image = (const float*)d_in[0];
  const float* ln1_g = (const float*)d_in[1];
  const float* ln1_b = (const float*)d_in[2];
  const float* W_emb = (const float*)d_in[3];
  const float* b_emb = (const float*)d_in[4];
  const float* ln2_g = (const float*)d_in[5];
  const float* ln2_b = (const float*)d_in[6];
  const float* pos   = (const float*)d_in[7];
  const float* norm_g= (const float*)d_in[8];
  const float* norm_b= (const float*)d_in[9];
  const float* WV    = (const float*)d_in[10];
  const float* WK    = (const float*)d_in[11];
  const float* WQ    = (const float*)d_in[12];
  const float* lastW = (const float*)d_in[13];
  const float* lastb = (const float*)d_in[14];
  float* out = (float*)d_out;

  char* W = (char*)d_ws;
  bf16*  x     = (bf16*) (W);                      // 25,690,112 (bf16 residual stream)
  bf16*  xnb   = (bf16*) (W + 51380224);           // 25,690,112
  bf16*  xm    = (bf16*) (W + 77070336);           // 25.7MB in 51.6MB slab (alias Xp; overread zone)
  bf16*  Xp    = xm;
  // slabB: embed-phase xn (fp32 51.4 MB) OR layer-phase Gt+Apad
  float* xn    = (float*)(W + 128712704);
  bf16*  Gt    = (bf16*) (W + 128712704);          // 29,360,128
  bf16*  Apad  = (bf16*) (W + 167907328);          //  7,340,032
  bf16*  WembT = (bf16*) (W + 180092928);          //  1,572,864
  bf16*  WQb   = (bf16*) (W + 181665792);          //  2,097,152 (natural layout)
  bf16*  WKb   = (bf16*) (W + 183762944);          //  2,097,152 (natural layout)
  bf16*  WVt   = (bf16*) (W + 185860096);          //     32,768
  bf16*  lastWT= (bf16*) (W + 185892864);          //  2,097,152
  bf16*  meanxb= (bf16*) (W + 187990016);          //    131,072
  float* clsPart=(float*)(W + 188121088);          //  2,097,152
  bf16*  Mt    = (bf16*) (W + 190218240);          //  2,097,152 (M^T = WK @ WQ^T)

  dim3 blk(256);
  const float scale = 0.08838834764831845f;  // 128^-0.5
  const long ZR = 0;

  // weight casts
  castT<<<dim3(32, 24), dim3(32, 8), 0, stream>>>(W_emb, WembT, PD, DIMD);
  castN<<<1024, blk, 0, stream>>>(WQ, (ushort4*)WQb);
  castN<<<1024, blk, 0, stream>>>(WK, (ushort4*)WKb);
  castT<<<dim3(4, 4),  dim3(32, 8), 0, stream>>>(WV, WVt, HD, HD);
  castT<<<dim3(32, 32), dim3(32, 8), 0, stream>>>(lastW, lastWT, DIMD, 1000);
  // Mt[j][i] = sum_k WK[j][k]*WQ[i][k]  (= (WQ @ WK^T)^T)
  gemm_mfma<<<dim3(8, 8, 1), blk, 0, stream>>>(
      WKb, DIMD, ZR, WQb, DIMD, ZR, DIMD, 1,
      nullptr, Mt, DIMD, ZR, nullptr, nullptr, ZR, 1.f, DIMD, DIMD);

  // patch embed
  patchify_ln<<<TOKENS, blk, 0, stream>>>(image, ln1_g, ln1_b, Xp);
  gemm_mfma<<<dim3(8, 98, 1), blk, 0, stream>>>(
      Xp, PD, ZR, WembT, PD, ZR, PD, 0,
      xn, nullptr, DIMD, ZR, b_emb, nullptr, ZR, 1.f, TOKENS, DIMD);
  ln_rows2<<<TOKENS, blk, 0, stream>>>(xn, ln2_g, ln2_b, pos, nullptr, (ushort4*)x);

  for (int l = 0; l < DEPTH; l++) {
    // xnb = bf16(LN(x))  (bf16 input)
    ln_rows_b<<<TOKENS, blk, 0, stream>>>((const ushort4*)x, norm_g, norm_b, (ushort4*)xnb);
    // xm = xnb @ M
    gemm_mfma<<<dim3(8, 98, 1), blk, 0, stream>>>(
        xnb, DIMD, ZR, Mt, DIMD, ZR, DIMD, 1,
        nullptr, xm, DIMD, ZR, nullptr, nullptr, ZR, 1.f, TOKENS, DIMD);
    // Apad = softmax(xm @ xnb^T * scale), fused, pads zeroed
    gemm_qs<<<dim3(1, 4, BATCH), blk, 0, stream>>>(xm, xnb, Apad, scale);
    // Gt[b][dim][tok] = WV^T @ xn^T  (direct transposed layout, pad cols zeroed)
    gemm_v<<<dim3(2, HEADS, BATCH), blk, 0, stream>>>(WVt, xnb, Gt);
    // x = bf16(Apad @ G + xnb)   (bf16 residual stream)
    gemm_mfma<<<dim3(8, 2, BATCH), blk, 0, stream>>>(
        Apad, APAD_C, (long)APAD_R*APAD_C, Gt, APAD_C, (long)DIMD*APAD_C, APAD_C, 1,
        nullptr, x, DIMD, (long)NTOK*DIMD, nullptr, xnb, (long)NTOK*DIMD, 1.f, NTOK, DIMD);
  }

  // classifier
  mean_tokens<<<dim3(BATCH, 4), blk, 0, stream>>>(x, meanxb);
  gemm_cls<<<dim3(8, 8), blk, 0, stream>>>(meanxb, lastWT, clsPart);
  cls_reduce<<<250, blk, 0, stream>>>(clsPart, lastb, out);
}